// Round 2
// baseline (660.341 us; speedup 1.0000x reference)
//
#include <hip/hip_runtime.h>
#include <math.h>

// Problem constants
static const int B_  = 4;
static const int CE_ = 128;
static const int CD_ = 256;
static const int HE_ = 256;   // = WE
static const int HD_ = 128;   // = WD
static const int N_  = 16;
#define PLANE  65536          // HE*WE
#define DPLANE 16384          // HD*WD
#define UPSCALE (127.0f/255.0f)

// ---------------------------------------------------------------------------
// K1: enc fused: per-pixel channel stats (max/mean/proj) AND per-channel
// row-pair partials (sum/max over the block's 512 pixels).
// grid = B*128 blocks (b, row-pair k), 512 threads (2 rows x 256 cols)
// ---------------------------------------------------------------------------
__global__ __launch_bounds__(512) void k_enc(
    const float* __restrict__ x, const float* __restrict__ sw1,
    const float* __restrict__ sb1, float* __restrict__ stats,
    float* __restrict__ psum, float* __restrict__ pmax) {
  int blk = blockIdx.x;
  int b = blk >> 7, k = blk & 127;
  int t = threadIdx.x;
  int h = 2 * k + (t >> 8);
  int w = t & 255;
  int lane = t & 63, wv = t >> 6;     // 8 waves
  __shared__ float sw[CE_];
  __shared__ float wsum[CE_ * 8], wmax[CE_ * 8];
  if (t < CE_) sw[t] = sw1[t];
  __syncthreads();
  const float* base = x + (((size_t)b * CE_) * HE_ + h) * (size_t)HE_ + w;
  float mx = -INFINITY, sm = 0.f, pj = 0.f;
#pragma unroll 4
  for (int c = 0; c < CE_; ++c) {
    float v = base[(size_t)c << 16];
    mx = fmaxf(mx, v);
    sm += v;
    pj = fmaf(v, sw[c], pj);
    float s = v, m = v;
#pragma unroll
    for (int off = 32; off > 0; off >>= 1) {
      s += __shfl_xor(s, off);
      m = fmaxf(m, __shfl_xor(m, off));
    }
    if (lane == 0) { wsum[c * 8 + wv] = s; wmax[c * 8 + wv] = m; }
  }
  __syncthreads();
  // per-pixel stats (planes 0..2)
  size_t o = (((size_t)b * 6) * HE_ + h) * (size_t)HE_ + w;
  stats[o] = mx;
  stats[o + PLANE] = sm * (1.f / CE_);
  stats[o + 2 * PLANE] = pj + sb1[0];
  // per-channel partials for this row pair
  if (t < CE_) {
    float4 q0 = *(float4*)&wsum[t * 8];
    float4 q1 = *(float4*)&wsum[t * 8 + 4];
    float s = (q0.x + q0.y) + (q0.z + q0.w) + (q1.x + q1.y) + (q1.z + q1.w);
    float4 r0 = *(float4*)&wmax[t * 8];
    float4 r1 = *(float4*)&wmax[t * 8 + 4];
    float m = fmaxf(fmaxf(fmaxf(r0.x, r0.y), fmaxf(r0.z, r0.w)),
                    fmaxf(fmaxf(r1.x, r1.y), fmaxf(r1.z, r1.w)));
    psum[(((b << 7) | k) << 7) | t] = s;
    pmax[(((b << 7) | k) << 7) | t] = m;
  }
}

// ---------------------------------------------------------------------------
// K2: dec fused: bilinear-up2x(align_corners)+relu computed on the fly from
// LDS-staged input rows; produces per-pixel stats (planes 3..5) AND
// per-channel partials (sum/max over the block's 4 output rows).
// grid = B*64 blocks (b, 4-row group), 512 threads (2 row-pairs x 256 cols)
// ---------------------------------------------------------------------------
__global__ __launch_bounds__(512) void k_dec(
    const float* __restrict__ x, const float* __restrict__ sw1,
    const float* __restrict__ sb1, float* __restrict__ stats,
    float* __restrict__ psum, float* __restrict__ pmax) {
  int blk = blockIdx.x;
  int b = blk >> 6, k = blk & 63;
  int t = threadIdx.x;
  int lane = t & 63, wv = t >> 6;     // 8 waves
  int h0 = 4 * k;
  __shared__ float sw[CD_];
  __shared__ float stage[2][512];
  __shared__ float wsum[CD_ * 8], wmax[CD_ * 8];
  if (t < CD_) sw[t] = sw1[t];
  int hA = h0 + ((t >> 8) << 1);      // rows h0,h0+1 (t<256) / h0+2,h0+3
  int hB = hA + 1;
  int w = t & 255;
  // column interpolation (identical arithmetic to reference)
  float pw = (float)w * UPSCALE;
  int iw0 = (int)pw; float fw = pw - (float)iw0;
  int iw1 = min(iw0 + 1, HD_ - 1);
  // row interpolation for the thread's two output rows
  float phA = (float)hA * UPSCALE;
  int a0 = (int)phA; float fA = phA - (float)a0;
  int a1 = min(a0 + 1, HD_ - 1);
  float phB = (float)hB * UPSCALE;
  int b0 = (int)phB; float fB = phB - (float)b0;
  int b1 = min(b0 + 1, HD_ - 1);
  int rmin = (int)((float)h0 * UPSCALE);   // block-uniform base input row
  int rA0 = a0 - rmin, rA1 = a1 - rmin;    // all in [0,3]
  int rB0 = b0 - rmin, rB1 = b1 - rmin;
  // staging assignment (threads 0..127 load float4)
  int srow = min(rmin + (t >> 5), HD_ - 1);
  int scol = (t & 31) * 4;
  const float* xb = x + (size_t)b * CD_ * DPLANE;
  float mxA = -INFINITY, smA = 0.f, pjA = 0.f;
  float mxB = -INFINITY, smB = 0.f, pjB = 0.f;
  __syncthreads();   // sw ready
  for (int c = 0; c < CD_; ++c) {
    int bi = c & 1;
    if (t < 128) {
      float4 v = *(const float4*)(xb + (size_t)c * DPLANE + srow * HD_ + scol);
      *(float4*)&stage[bi][(t >> 5) * HD_ + scol] = v;
    }
    __syncthreads();
    const float* S = stage[bi];
    float tA0 = S[rA0 * HD_ + iw0], tA1 = S[rA0 * HD_ + iw1];
    float uA0 = S[rA1 * HD_ + iw0], uA1 = S[rA1 * HD_ + iw1];
    float topA = tA0 + fw * (tA1 - tA0);
    float botA = uA0 + fw * (uA1 - uA0);
    float vA = fmaxf(topA + fA * (botA - topA), 0.f);
    float tB0 = S[rB0 * HD_ + iw0], tB1 = S[rB0 * HD_ + iw1];
    float uB0 = S[rB1 * HD_ + iw0], uB1 = S[rB1 * HD_ + iw1];
    float topB = tB0 + fw * (tB1 - tB0);
    float botB = uB0 + fw * (uB1 - uB0);
    float vB = fmaxf(topB + fB * (botB - topB), 0.f);
    mxA = fmaxf(mxA, vA); smA += vA; pjA = fmaf(vA, sw[c], pjA);
    mxB = fmaxf(mxB, vB); smB += vB; pjB = fmaf(vB, sw[c], pjB);
    float s = vA + vB, m = fmaxf(vA, vB);
#pragma unroll
    for (int off = 32; off > 0; off >>= 1) {
      s += __shfl_xor(s, off);
      m = fmaxf(m, __shfl_xor(m, off));
    }
    if (lane == 0) { wsum[c * 8 + wv] = s; wmax[c * 8 + wv] = m; }
  }
  __syncthreads();
  // per-pixel stats (planes 3..5) for both rows
  size_t oA = (((size_t)b * 6 + 3) * HE_ + hA) * (size_t)HE_ + w;
  stats[oA] = mxA;
  stats[oA + PLANE] = smA * (1.f / CD_);
  stats[oA + 2 * PLANE] = pjA + sb1[0];
  size_t oB = (((size_t)b * 6 + 3) * HE_ + hB) * (size_t)HE_ + w;
  stats[oB] = mxB;
  stats[oB + PLANE] = smB * (1.f / CD_);
  stats[oB + 2 * PLANE] = pjB + sb1[0];
  // per-channel partials for this 4-row group
  if (t < CD_) {
    float4 q0 = *(float4*)&wsum[t * 8];
    float4 q1 = *(float4*)&wsum[t * 8 + 4];
    float s = (q0.x + q0.y) + (q0.z + q0.w) + (q1.x + q1.y) + (q1.z + q1.w);
    float4 r0 = *(float4*)&wmax[t * 8];
    float4 r1 = *(float4*)&wmax[t * 8 + 4];
    float m = fmaxf(fmaxf(fmaxf(r0.x, r0.y), fmaxf(r0.z, r0.w)),
                    fmaxf(fmaxf(r1.x, r1.y), fmaxf(r1.z, r1.w)));
    psum[(((b << 6) | k) << 8) | t] = s;
    pmax[(((b << 6) | k) << 8) | t] = m;
  }
}

// ---------------------------------------------------------------------------
// K3: reduce partials -> eav/emx (512 blocks) and dav/dmx (1024 blocks)
// ---------------------------------------------------------------------------
__global__ __launch_bounds__(128) void k_red(
    const float* __restrict__ pse, const float* __restrict__ pme,
    const float* __restrict__ psd, const float* __restrict__ pmd,
    float* __restrict__ eav, float* __restrict__ emx,
    float* __restrict__ dav, float* __restrict__ dmx) {
  int id = blockIdx.x, t = threadIdx.x;
  int lane = t & 63, wv = t >> 6;
  float s = 0.f, m = -INFINITY;
  if (id < 512) {
    int b = id >> 7, c = id & 127;
    size_t off = ((((size_t)b << 7) | t) << 7) | c;
    s = pse[off]; m = pme[off];
  } else {
    int j = id - 512;
    int b = j >> 8, c = j & 255;
    if (t < 64) {
      size_t off = ((((size_t)b << 6) | t) << 8) | c;
      s = psd[off]; m = pmd[off];
    }
  }
#pragma unroll
  for (int off = 32; off > 0; off >>= 1) {
    s += __shfl_xor(s, off);
    m = fmaxf(m, __shfl_xor(m, off));
  }
  __shared__ float s2[2], m2[2];
  if (lane == 0) { s2[wv] = s; m2[wv] = m; }
  __syncthreads();
  if (t == 0) {
    float S = s2[0] + s2[1], M = fmaxf(m2[0], m2[1]);
    if (id < 512) { eav[id] = S * (1.f / PLANE); emx[id] = M; }
    else { dav[id - 512] = S * (1.f / PLANE); dmx[id - 512] = M; }
  }
}

// ---------------------------------------------------------------------------
// K4: spatial attention: spat = sigmoid(conv7(enc_stats)+conv7(dec_stats)+b)
// ---------------------------------------------------------------------------
__global__ __launch_bounds__(256) void k_sag(
    const float* __restrict__ stats, const float* __restrict__ we,
    const float* __restrict__ be, const float* __restrict__ wd,
    const float* __restrict__ bd, float* __restrict__ spat) {
  int bh = blockIdx.x;
  int b = bh >> 8, h = bh & 255;
  int w = threadIdx.x;
  __shared__ float swE[147], swD[147];
  if (threadIdx.x < 147) { swE[threadIdx.x] = we[threadIdx.x]; swD[threadIdx.x] = wd[threadIdx.x]; }
  __syncthreads();
  float acc = be[0] + bd[0];
  const float* sb = stats + ((size_t)b * 6) * PLANE;
#pragma unroll
  for (int ic = 0; ic < 3; ++ic) {
    const float* pe = sb + (size_t)ic * PLANE;
    const float* pd = sb + (size_t)(ic + 3) * PLANE;
#pragma unroll
    for (int ky = 0; ky < 7; ++ky) {
      int y = h + ky - 3;
      if ((unsigned)y >= 256u) continue;
      const float* rowE = pe + y * 256;
      const float* rowD = pd + y * 256;
#pragma unroll
      for (int kx = 0; kx < 7; ++kx) {
        int xw = w + kx - 3;
        if ((unsigned)xw >= 256u) continue;
        acc = fmaf(rowE[xw], swE[ic * 49 + ky * 7 + kx], acc);
        acc = fmaf(rowD[xw], swD[ic * 49 + ky * 7 + kx], acc);
      }
    }
  }
  spat[(size_t)b * PLANE + h * 256 + w] = 1.f / (1.f + __expf(-acc));
}

// ---------------------------------------------------------------------------
// K5: channel attention (tiny MLP)
// ---------------------------------------------------------------------------
__global__ __launch_bounds__(512) void k_cag(
    const float* __restrict__ eav, const float* __restrict__ emx,
    const float* __restrict__ dav, const float* __restrict__ dmx,
    const float* __restrict__ cw_ea, const float* __restrict__ cb_ea,
    const float* __restrict__ cw_em, const float* __restrict__ cb_em,
    const float* __restrict__ cw_da, const float* __restrict__ cb_da,
    const float* __restrict__ cw_dm, const float* __restrict__ cb_dm,
    const float* __restrict__ cw_f, const float* __restrict__ cb_f,
    float* __restrict__ ch) {
  __shared__ float scd[B_ * N_];
  int t = threadIdx.x;
  if (t < B_ * N_) {
    int b = t >> 4, n = t & 15;
    float s = cb_ea[n] + cb_em[n] + cb_da[n] + cb_dm[n];
    for (int c = 0; c < CE_; ++c)
      s += eav[b * CE_ + c] * cw_ea[n * CE_ + c] + emx[b * CE_ + c] * cw_em[n * CE_ + c];
    for (int c = 0; c < CD_; ++c)
      s += dav[b * CD_ + c] * cw_da[n * CD_ + c] + dmx[b * CD_ + c] * cw_dm[n * CD_ + c];
    scd[t] = s;
  }
  __syncthreads();
  int b = t >> 7, o = t & 127;
  float s = cb_f[o];
#pragma unroll
  for (int n = 0; n < N_; ++n) s += scd[b * N_ + n] * cw_f[o * N_ + n];
  ch[t] = 1.f / (1.f + __expf(-s));
}

// ---------------------------------------------------------------------------
// K6: final gate: out = x_enc * spat[b,hw] * ch[b,c]   (float4)
// ---------------------------------------------------------------------------
__global__ __launch_bounds__(256) void k_final(
    const float* __restrict__ x, const float* __restrict__ spat,
    const float* __restrict__ ch, float* __restrict__ out) {
  size_t i4 = (size_t)blockIdx.x * 256 + threadIdx.x;
  size_t e = i4 * 4;
  int b = (int)(e >> 23);
  int c = (int)((e >> 16) & 127);
  int p = (int)(e & 65535);
  float4 xv = ((const float4*)x)[i4];
  float4 sv = *(const float4*)(spat + ((size_t)b << 16) + p);
  float cv = ch[(b << 7) | c];
  float4 o;
  o.x = xv.x * sv.x * cv;
  o.y = xv.y * sv.y * cv;
  o.z = xv.z * sv.z * cv;
  o.w = xv.w * sv.w * cv;
  ((float4*)out)[i4] = o;
}

// ---------------------------------------------------------------------------
extern "C" void kernel_launch(void* const* d_in, const int* in_sizes, int n_in,
                              void* d_out, int out_size, void* d_ws, size_t ws_size,
                              hipStream_t stream) {
  const float* x_enc = (const float*)d_in[0];
  const float* x_dec = (const float*)d_in[1];
  const float* cw_ea = (const float*)d_in[2];
  const float* cb_ea = (const float*)d_in[3];
  const float* cw_em = (const float*)d_in[4];
  const float* cb_em = (const float*)d_in[5];
  const float* cw_da = (const float*)d_in[6];
  const float* cb_da = (const float*)d_in[7];
  const float* cw_dm = (const float*)d_in[8];
  const float* cb_dm = (const float*)d_in[9];
  const float* cw_f  = (const float*)d_in[10];
  const float* cb_f  = (const float*)d_in[11];
  const float* sw1_e = (const float*)d_in[12];
  const float* sb1_e = (const float*)d_in[13];
  const float* sw2_e = (const float*)d_in[14];
  const float* sb2_e = (const float*)d_in[15];
  const float* sw1_d = (const float*)d_in[16];
  const float* sb1_d = (const float*)d_in[17];
  const float* sw2_d = (const float*)d_in[18];
  const float* sb2_d = (const float*)d_in[19];
  float* out = (float*)d_out;

  // workspace layout (floats) — total 1,838,592 floats = 7.35 MB
  float* ws     = (float*)d_ws;
  float* stats  = ws;                  // B*6*PLANE = 1,572,864
  float* part   = ws + 1572864;        // 262,144 (partials; later aliased by spat)
  float* pse    = part;                //  65,536  enc sum  [b][k128][c128]
  float* pme    = part + 65536;        //  65,536  enc max
  float* psd    = part + 131072;       //  65,536  dec sum  [b][k64][c256]
  float* pmd    = part + 196608;       //  65,536  dec max
  float* spat   = part;                // aliases partials (consumed by k_red first)
  float* eav    = ws + 1835008;        // 512
  float* emx    = eav + 512;           // 512
  float* dav    = emx + 512;           // 1024
  float* dmx    = dav + 1024;          // 1024
  float* chn    = dmx + 1024;          // 512

  k_enc  <<<B_ * 128, 512, 0, stream>>>(x_enc, sw1_e, sb1_e, stats, pse, pme);
  k_dec  <<<B_ * 64, 512, 0, stream>>>(x_dec, sw1_d, sb1_d, stats, psd, pmd);
  k_red  <<<1536, 128, 0, stream>>>(pse, pme, psd, pmd, eav, emx, dav, dmx);
  k_sag  <<<B_ * HE_, 256, 0, stream>>>(stats, sw2_e, sb2_e, sw2_d, sb2_d, spat);
  k_cag  <<<1, 512, 0, stream>>>(eav, emx, dav, dmx,
                                 cw_ea, cb_ea, cw_em, cb_em,
                                 cw_da, cb_da, cw_dm, cb_dm,
                                 cw_f, cb_f, chn);
  k_final<<<(out_size / 4 + 255) / 256, 256, 0, stream>>>(x_enc, spat, chn, out);
}

// Round 3
// 564.354 us; speedup vs baseline: 1.1701x; 1.1701x over previous
//
#include <hip/hip_runtime.h>
#include <math.h>

// Problem constants
static const int B_  = 4;
static const int CE_ = 128;
static const int CD_ = 256;
static const int HE_ = 256;   // = WE
static const int HD_ = 128;   // = WD
static const int N_  = 16;
#define PLANE  65536          // HE*WE
#define DPLANE 16384          // HD*WD
#define UPSCALE (127.0f/255.0f)

// ---------------------------------------------------------------------------
// K1: enc per-pixel channel stats: max_c, mean_c, proj_c(sw1_e)+sb1_e
// grid = B*HE blocks (b,row), 256 threads (col). Coalesced 256B/wave loads.
// ---------------------------------------------------------------------------
__global__ __launch_bounds__(256) void k_enc_pix(
    const float* __restrict__ x, const float* __restrict__ sw1,
    const float* __restrict__ sb1, float* __restrict__ stats) {
  int bh = blockIdx.x;
  int b = bh >> 8, h = bh & 255;
  int w = threadIdx.x;
  __shared__ float sw[CE_];
  if (threadIdx.x < CE_) sw[threadIdx.x] = sw1[threadIdx.x];
  __syncthreads();
  const float* base = x + (((size_t)b * CE_) * HE_ + h) * (size_t)HE_ + w;
  float mx = -INFINITY, sm = 0.f, pj = 0.f;
#pragma unroll 4
  for (int c = 0; c < CE_; ++c) {
    float v = base[(size_t)c << 16];
    mx = fmaxf(mx, v);
    sm += v;
    pj = fmaf(v, sw[c], pj);
  }
  size_t o = (((size_t)b * 6) * HE_ + h) * (size_t)HE_ + w;
  stats[o] = mx;
  stats[o + PLANE] = sm * (1.f / CE_);
  stats[o + 2 * PLANE] = pj + sb1[0];
}

// ---------------------------------------------------------------------------
// K2: enc per-channel spatial stats (mean/max over plane). float4 streaming.
// grid = B*CE blocks, 256 threads.
// ---------------------------------------------------------------------------
__global__ __launch_bounds__(256) void k_enc_chan(
    const float* __restrict__ x, float* __restrict__ av, float* __restrict__ mx) {
  int bc = blockIdx.x;
  const float4* p = (const float4*)(x + (size_t)bc * PLANE);
  float sm = 0.f, m = -INFINITY;
  for (int i = threadIdx.x; i < PLANE / 4; i += 256) {
    float4 v = p[i];
    sm += (v.x + v.y) + (v.z + v.w);
    m = fmaxf(m, fmaxf(fmaxf(v.x, v.y), fmaxf(v.z, v.w)));
  }
  __shared__ float ss[256], sx[256];
  int t = threadIdx.x;
  ss[t] = sm; sx[t] = m;
  __syncthreads();
  for (int s = 128; s > 0; s >>= 1) {
    if (t < s) { ss[t] += ss[t + s]; sx[t] = fmaxf(sx[t], sx[t + s]); }
    __syncthreads();
  }
  if (t == 0) { av[bc] = ss[0] * (1.f / PLANE); mx[bc] = sx[0]; }
}

// ---------------------------------------------------------------------------
// K3: dec per-pixel channel stats, bilinear-up2x(align_corners)+relu on the
// fly. Block = (b, output row-pair m): rows 2m, 2m+1 share input rows
// r0..r0+2 (block-uniform). Thread = col. 6 scalar gathers/channel, no
// barriers in the loop -> loads pipeline freely; L3 absorbs the 1-row halo.
// grid = B*128 blocks, 256 threads.
// ---------------------------------------------------------------------------
__global__ __launch_bounds__(256) void k_dec_pix(
    const float* __restrict__ x, const float* __restrict__ sw1,
    const float* __restrict__ sb1, float* __restrict__ stats) {
  int blk = blockIdx.x;
  int b = blk >> 7, m = blk & 127;
  int w = threadIdx.x;
  __shared__ float sw[CD_];
  sw[w] = sw1[w];
  __syncthreads();
  int hA = 2 * m, hB = 2 * m + 1;
  // block-uniform row interpolation params
  float pA = (float)hA * UPSCALE;
  int iA0 = (int)pA; float fA = pA - (float)iA0;   // iA0 <= 126
  float pB = (float)hB * UPSCALE;
  int iB0 = (int)pB; float fB = pB - (float)iB0;
  int d = iB0 - iA0;                                // 0 or 1
  int r2o = (min(iA0 + 2, HD_ - 1) - iA0) * HD_;    // offset of 3rd row
  // per-lane column interpolation
  float pw = (float)w * UPSCALE;
  int iw0 = (int)pw; float f = pw - (float)iw0;
  int iw1 = min(iw0 + 1, HD_ - 1);
  const float* base = x + (size_t)b * CD_ * DPLANE + iA0 * HD_;
  int o0a = iw0, o0b = iw1;
  int o1a = HD_ + iw0, o1b = HD_ + iw1;
  int o2a = r2o + iw0, o2b = r2o + iw1;
  float mxA = -INFINITY, smA = 0.f, pjA = 0.f;
  float mxB = -INFINITY, smB = 0.f, pjB = 0.f;
#pragma unroll 2
  for (int c = 0; c < CD_; ++c) {
    float L0a = base[o0a], L0b = base[o0b];
    float L1a = base[o1a], L1b = base[o1b];
    float L2a = base[o2a], L2b = base[o2b];
    base += DPLANE;
    float topA = fmaf(f, L0b - L0a, L0a);
    float botA = fmaf(f, L1b - L1a, L1a);
    float vA = fmaxf(fmaf(fA, botA - topA, topA), 0.f);
    float B0a = d ? L1a : L0a, B0b = d ? L1b : L0b;
    float B1a = d ? L2a : L1a, B1b = d ? L2b : L1b;
    float topB = fmaf(f, B0b - B0a, B0a);
    float botB = fmaf(f, B1b - B1a, B1a);
    float vB = fmaxf(fmaf(fB, botB - topB, topB), 0.f);
    mxA = fmaxf(mxA, vA); smA += vA; pjA = fmaf(vA, sw[c], pjA);
    mxB = fmaxf(mxB, vB); smB += vB; pjB = fmaf(vB, sw[c], pjB);
  }
  size_t oA = (((size_t)b * 6 + 3) * HE_ + hA) * (size_t)HE_ + w;
  stats[oA] = mxA;
  stats[oA + PLANE] = smA * (1.f / CD_);
  stats[oA + 2 * PLANE] = pjA + sb1[0];
  size_t oB = (((size_t)b * 6 + 3) * HE_ + hB) * (size_t)HE_ + w;
  stats[oB] = mxB;
  stats[oB + PLANE] = smB * (1.f / CD_);
  stats[oB + 2 * PLANE] = pjB + sb1[0];
}

// ---------------------------------------------------------------------------
// K4: dec per-channel spatial stats over the virtual upsampled+relu plane.
// grid = B*CD blocks (b,c), 256 threads (col); row-pair loop, loads L1-hot.
// ---------------------------------------------------------------------------
__global__ __launch_bounds__(256) void k_dec_chan(
    const float* __restrict__ x, float* __restrict__ av, float* __restrict__ mxo) {
  int bc = blockIdx.x;
  const float* p = x + (size_t)bc * DPLANE;
  int w = threadIdx.x;
  float pw = (float)w * UPSCALE;
  int iw0 = (int)pw; float f = pw - (float)iw0;
  int iw1 = min(iw0 + 1, HD_ - 1);
  float sm = 0.f, mv = -INFINITY;
  for (int m = 0; m < 128; ++m) {
    int hA = 2 * m, hB = 2 * m + 1;
    float pA = (float)hA * UPSCALE;
    int iA0 = (int)pA; float fA = pA - (float)iA0;
    float pB = (float)hB * UPSCALE;
    int iB0 = (int)pB; float fB = pB - (float)iB0;
    int d = iB0 - iA0;
    int r2o = (min(iA0 + 2, HD_ - 1) - iA0) * HD_;
    const float* r = p + iA0 * HD_;
    float L0a = r[iw0], L0b = r[iw1];
    float L1a = r[HD_ + iw0], L1b = r[HD_ + iw1];
    float L2a = r[r2o + iw0], L2b = r[r2o + iw1];
    float topA = fmaf(f, L0b - L0a, L0a);
    float botA = fmaf(f, L1b - L1a, L1a);
    float vA = fmaxf(fmaf(fA, botA - topA, topA), 0.f);
    float B0a = d ? L1a : L0a, B0b = d ? L1b : L0b;
    float B1a = d ? L2a : L1a, B1b = d ? L2b : L1b;
    float topB = fmaf(f, B0b - B0a, B0a);
    float botB = fmaf(f, B1b - B1a, B1a);
    float vB = fmaxf(fmaf(fB, botB - topB, topB), 0.f);
    sm += vA + vB;
    mv = fmaxf(mv, fmaxf(vA, vB));
  }
  __shared__ float ss[256], sx[256];
  int t = threadIdx.x;
  ss[t] = sm; sx[t] = mv;
  __syncthreads();
  for (int s = 128; s > 0; s >>= 1) {
    if (t < s) { ss[t] += ss[t + s]; sx[t] = fmaxf(sx[t], sx[t + s]); }
    __syncthreads();
  }
  if (t == 0) { av[bc] = ss[0] * (1.f / PLANE); mxo[bc] = sx[0]; }
}

// ---------------------------------------------------------------------------
// K5: spatial attention: spat = sigmoid(conv7(enc_stats)+conv7(dec_stats)+b)
// ---------------------------------------------------------------------------
__global__ __launch_bounds__(256) void k_sag(
    const float* __restrict__ stats, const float* __restrict__ we,
    const float* __restrict__ be, const float* __restrict__ wd,
    const float* __restrict__ bd, float* __restrict__ spat) {
  int bh = blockIdx.x;
  int b = bh >> 8, h = bh & 255;
  int w = threadIdx.x;
  __shared__ float swE[147], swD[147];
  if (threadIdx.x < 147) { swE[threadIdx.x] = we[threadIdx.x]; swD[threadIdx.x] = wd[threadIdx.x]; }
  __syncthreads();
  float acc = be[0] + bd[0];
  const float* sb = stats + ((size_t)b * 6) * PLANE;
#pragma unroll
  for (int ic = 0; ic < 3; ++ic) {
    const float* pe = sb + (size_t)ic * PLANE;
    const float* pd = sb + (size_t)(ic + 3) * PLANE;
#pragma unroll
    for (int ky = 0; ky < 7; ++ky) {
      int y = h + ky - 3;
      if ((unsigned)y >= 256u) continue;
      const float* rowE = pe + y * 256;
      const float* rowD = pd + y * 256;
#pragma unroll
      for (int kx = 0; kx < 7; ++kx) {
        int xw = w + kx - 3;
        if ((unsigned)xw >= 256u) continue;
        acc = fmaf(rowE[xw], swE[ic * 49 + ky * 7 + kx], acc);
        acc = fmaf(rowD[xw], swD[ic * 49 + ky * 7 + kx], acc);
      }
    }
  }
  spat[(size_t)b * PLANE + h * 256 + w] = 1.f / (1.f + __expf(-acc));
}

// ---------------------------------------------------------------------------
// K6: channel attention (tiny MLP)
// ---------------------------------------------------------------------------
__global__ __launch_bounds__(512) void k_cag(
    const float* __restrict__ eav, const float* __restrict__ emx,
    const float* __restrict__ dav, const float* __restrict__ dmx,
    const float* __restrict__ cw_ea, const float* __restrict__ cb_ea,
    const float* __restrict__ cw_em, const float* __restrict__ cb_em,
    const float* __restrict__ cw_da, const float* __restrict__ cb_da,
    const float* __restrict__ cw_dm, const float* __restrict__ cb_dm,
    const float* __restrict__ cw_f, const float* __restrict__ cb_f,
    float* __restrict__ ch) {
  __shared__ float scd[B_ * N_];
  int t = threadIdx.x;
  if (t < B_ * N_) {
    int b = t >> 4, n = t & 15;
    float s = cb_ea[n] + cb_em[n] + cb_da[n] + cb_dm[n];
    for (int c = 0; c < CE_; ++c)
      s += eav[b * CE_ + c] * cw_ea[n * CE_ + c] + emx[b * CE_ + c] * cw_em[n * CE_ + c];
    for (int c = 0; c < CD_; ++c)
      s += dav[b * CD_ + c] * cw_da[n * CD_ + c] + dmx[b * CD_ + c] * cw_dm[n * CD_ + c];
    scd[t] = s;
  }
  __syncthreads();
  int b = t >> 7, o = t & 127;
  float s = cb_f[o];
#pragma unroll
  for (int n = 0; n < N_; ++n) s += scd[b * N_ + n] * cw_f[o * N_ + n];
  ch[t] = 1.f / (1.f + __expf(-s));
}

// ---------------------------------------------------------------------------
// K7: final gate: out = x_enc * spat[b,hw] * ch[b,c]   (float4)
// ---------------------------------------------------------------------------
__global__ __launch_bounds__(256) void k_final(
    const float* __restrict__ x, const float* __restrict__ spat,
    const float* __restrict__ ch, float* __restrict__ out) {
  size_t i4 = (size_t)blockIdx.x * 256 + threadIdx.x;
  size_t e = i4 * 4;
  int b = (int)(e >> 23);
  int c = (int)((e >> 16) & 127);
  int p = (int)(e & 65535);
  float4 xv = ((const float4*)x)[i4];
  float4 sv = *(const float4*)(spat + ((size_t)b << 16) + p);
  float cv = ch[(b << 7) | c];
  float4 o;
  o.x = xv.x * sv.x * cv;
  o.y = xv.y * sv.y * cv;
  o.z = xv.z * sv.z * cv;
  o.w = xv.w * sv.w * cv;
  ((float4*)out)[i4] = o;
}

// ---------------------------------------------------------------------------
extern "C" void kernel_launch(void* const* d_in, const int* in_sizes, int n_in,
                              void* d_out, int out_size, void* d_ws, size_t ws_size,
                              hipStream_t stream) {
  const float* x_enc = (const float*)d_in[0];
  const float* x_dec = (const float*)d_in[1];
  const float* cw_ea = (const float*)d_in[2];
  const float* cb_ea = (const float*)d_in[3];
  const float* cw_em = (const float*)d_in[4];
  const float* cb_em = (const float*)d_in[5];
  const float* cw_da = (const float*)d_in[6];
  const float* cb_da = (const float*)d_in[7];
  const float* cw_dm = (const float*)d_in[8];
  const float* cb_dm = (const float*)d_in[9];
  const float* cw_f  = (const float*)d_in[10];
  const float* cb_f  = (const float*)d_in[11];
  const float* sw1_e = (const float*)d_in[12];
  const float* sb1_e = (const float*)d_in[13];
  const float* sw2_e = (const float*)d_in[14];
  const float* sb2_e = (const float*)d_in[15];
  const float* sw1_d = (const float*)d_in[16];
  const float* sb1_d = (const float*)d_in[17];
  const float* sw2_d = (const float*)d_in[18];
  const float* sb2_d = (const float*)d_in[19];
  float* out = (float*)d_out;

  // workspace layout (floats) — total 1,838,592 = 7.35 MB
  float* ws    = (float*)d_ws;
  float* stats = ws;                  // B*6*PLANE = 1,572,864
  float* spat  = ws + 1572864;        // B*PLANE   =   262,144
  float* eav   = ws + 1835008;        // 512
  float* emx   = eav + 512;           // 512
  float* dav   = emx + 512;           // 1024
  float* dmx   = dav + 1024;          // 1024
  float* chn   = dmx + 1024;          // 512

  k_enc_pix <<<B_ * HE_, 256, 0, stream>>>(x_enc, sw1_e, sb1_e, stats);
  k_enc_chan<<<B_ * CE_, 256, 0, stream>>>(x_enc, eav, emx);
  k_dec_pix <<<B_ * 128, 256, 0, stream>>>(x_dec, sw1_d, sb1_d, stats);
  k_dec_chan<<<B_ * CD_, 256, 0, stream>>>(x_dec, dav, dmx);
  k_sag     <<<B_ * HE_, 256, 0, stream>>>(stats, sw2_e, sb2_e, sw2_d, sb2_d, spat);
  k_cag     <<<1, 512, 0, stream>>>(eav, emx, dav, dmx,
                                    cw_ea, cb_ea, cw_em, cb_em,
                                    cw_da, cb_da, cw_dm, cb_dm,
                                    cw_f, cb_f, chn);
  k_final   <<<(out_size / 4 + 255) / 256, 256, 0, stream>>>(x_enc, spat, chn, out);
}